// Round 1
// baseline (786.953 us; speedup 1.0000x reference)
//
#include <hip/hip_runtime.h>
#include <hip/hip_bf16.h>

#define IMG 8        // B*S images per stream
#define C   64       // channels
#define Hh  128
#define Ww  128
#define HW  16384    // H*W

// ---------------------------------------------------------------------------
// Kernel 1: 1x1 conv + BN + ReLU.  y[img,co,p] = relu(scale[co]*Σ_ci w[co,ci]*x[img,ci,p] + shift[co])
// grid: (HW/256, IMG). Weights read through scalar cache (uniform addresses).
// ---------------------------------------------------------------------------
__global__ __launch_bounds__(256) void proj_kernel(
    const float* __restrict__ x, const float* __restrict__ w,
    const float* __restrict__ gamma, const float* __restrict__ beta,
    const float* __restrict__ mean, const float* __restrict__ var,
    float* __restrict__ y)
{
    const int img = blockIdx.y;
    const int pix = blockIdx.x * 256 + threadIdx.x;
    const float* xi = x + (size_t)img * C * HW;
    float xr[C];
#pragma unroll
    for (int ci = 0; ci < C; ++ci) xr[ci] = xi[(size_t)ci * HW + pix];

    float* yo = y + (size_t)img * C * HW;
    for (int co = 0; co < C; ++co) {
        float acc = 0.f;
#pragma unroll
        for (int ci = 0; ci < C; ++ci) acc = fmaf(w[co * C + ci], xr[ci], acc);
        const float s  = gamma[co] * rsqrtf(var[co] + 1e-5f);
        const float sh = fmaf(-mean[co], s, beta[co]);
        const float r  = fmaf(acc, s, sh);
        yo[(size_t)co * HW + pix] = fmaxf(r, 0.f);
    }
}

// ---------------------------------------------------------------------------
// Kernel 2: 3x3 conv, pad=1 (cross-correlation, NCHW/OIHW).
// Block = 256 threads = 8h x 32w output tile, 16 output channels/block.
// Input tile staged in LDS per 16-ci chunk; weights via scalar cache.
// grid: (64 pixel tiles, 4 co groups, 8 images)
// ---------------------------------------------------------------------------
#define TH 8
#define TW 32
#define CO_T 16
#define CI_T 16

__global__ __launch_bounds__(256) void conv3x3_kernel(
    const float* __restrict__ x, const float* __restrict__ w,
    float* __restrict__ y, int wStrideCi, int ciOffset)
{
    __shared__ float xs[CI_T][TH + 2][TW + 3];   // +3 pad: conflict-free rows

    const int img  = blockIdx.z;
    const int cog  = blockIdx.y;
    const int tile = blockIdx.x;
    const int ty = tile >> 2, tx = tile & 3;
    const int h0 = ty * TH, w0 = tx * TW;
    const int tid = threadIdx.x;
    const int lr = tid / TW, lc = tid % TW;

    float acc[CO_T];
#pragma unroll
    for (int i = 0; i < CO_T; ++i) acc[i] = 0.f;

    const float* xi = x + (size_t)img * C * HW;

    for (int cb = 0; cb < C; cb += CI_T) {
        __syncthreads();   // protect LDS from previous iteration's readers
        // ---- stage (cb..cb+15) x 10 x 34 input window (zero-padded) ----
        for (int idx = tid; idx < CI_T * (TH + 2) * (TW + 2); idx += 256) {
            const int ci  = idx / ((TH + 2) * (TW + 2));
            const int rem = idx % ((TH + 2) * (TW + 2));
            const int r = rem / (TW + 2), c = rem % (TW + 2);
            const int gh = h0 + r - 1, gw = w0 + c - 1;
            float val = 0.f;
            if (gh >= 0 && gh < Hh && gw >= 0 && gw < Ww)
                val = xi[(size_t)(cb + ci) * HW + gh * Ww + gw];
            xs[ci][r][c] = val;
        }
        __syncthreads();
        // ---- accumulate ----
        for (int ci = 0; ci < CI_T; ++ci) {
            float xv[9];
#pragma unroll
            for (int ky = 0; ky < 3; ++ky)
#pragma unroll
                for (int kx = 0; kx < 3; ++kx)
                    xv[ky * 3 + kx] = xs[ci][lr + ky][lc + kx];
#pragma unroll
            for (int co = 0; co < CO_T; ++co) {
                const float* wp = w + ((size_t)(cog * CO_T + co) * wStrideCi + ciOffset + cb + ci) * 9;
#pragma unroll
                for (int k = 0; k < 9; ++k) acc[co] = fmaf(wp[k], xv[k], acc[co]);
            }
        }
    }

    float* yo = y + ((size_t)img * C + cog * CO_T) * HW + (h0 + lr) * Ww + (w0 + lc);
#pragma unroll
    for (int co = 0; co < CO_T; ++co) yo[(size_t)co * HW] = acc[co];
}

// ---------------------------------------------------------------------------
// Kernel 3: cross broadcast add.
// out[b,sx,sy,co,hw] = ou[b*4+sx,co,hw] + ov[b*4+sy,co,hw] + bias[co]
// float4 vectorized; one thread per float4.
// ---------------------------------------------------------------------------
__global__ __launch_bounds__(256) void addb_kernel(
    const float* __restrict__ ou, const float* __restrict__ ov,
    const float* __restrict__ bias, float* __restrict__ out)
{
    const size_t i4 = (size_t)blockIdx.x * 256 + threadIdx.x;  // one float4
    const int    hw4 = (int)(i4 & 4095);           // HW/4 = 4096
    const size_t q   = i4 >> 12;                   // (b,sx,sy,co)
    const int co = (int)(q & 63);
    const size_t p = q >> 6;                       // b*16 + sx*4 + sy
    const int sy = (int)(p & 3);
    const int sx = (int)((p >> 2) & 3);
    const int b  = (int)(p >> 4);

    const float4 o1 = ((const float4*)ou)[((size_t)(b * 4 + sx) * C + co) * 4096 + hw4];
    const float4 o2 = ((const float4*)ov)[((size_t)(b * 4 + sy) * C + co) * 4096 + hw4];
    const float bb = bias[co];
    float4 r;
    r.x = o1.x + o2.x + bb;
    r.y = o1.y + o2.y + bb;
    r.z = o1.z + o2.z + bb;
    r.w = o1.w + o2.w + bb;
    ((float4*)out)[i4] = r;
}

// ---------------------------------------------------------------------------
extern "C" void kernel_launch(void* const* d_in, const int* in_sizes, int n_in,
                              void* d_out, int out_size, void* d_ws, size_t ws_size,
                              hipStream_t stream)
{
    const float* u        = (const float*)d_in[0];
    const float* v        = (const float*)d_in[1];
    const float* pu_w     = (const float*)d_in[2];
    const float* pu_gamma = (const float*)d_in[3];
    const float* pu_beta  = (const float*)d_in[4];
    const float* pu_mean  = (const float*)d_in[5];
    const float* pu_var   = (const float*)d_in[6];
    const float* pv_w     = (const float*)d_in[7];
    const float* pv_gamma = (const float*)d_in[8];
    const float* pv_beta  = (const float*)d_in[9];
    const float* pv_mean  = (const float*)d_in[10];
    const float* pv_var   = (const float*)d_in[11];
    const float* conv_w   = (const float*)d_in[12];
    const float* conv_b   = (const float*)d_in[13];
    float* out = (float*)d_out;

    const size_t nImg = (size_t)IMG * C * HW;   // 8,388,608 floats per buffer
    float* uf = (float*)d_ws;
    float* vf = uf + nImg;
    float* ou = vf + nImg;
    float* ov = ou + nImg;
    // needs 4 * 33.55 MB = 134.2 MB of workspace

    dim3 g1(HW / 256, IMG);
    proj_kernel<<<g1, 256, 0, stream>>>(u, pu_w, pu_gamma, pu_beta, pu_mean, pu_var, uf);
    proj_kernel<<<g1, 256, 0, stream>>>(v, pv_w, pv_gamma, pv_beta, pv_mean, pv_var, vf);

    dim3 g2(64, C / CO_T, IMG);
    conv3x3_kernel<<<g2, 256, 0, stream>>>(uf, conv_w, ou, 2 * C, 0);
    conv3x3_kernel<<<g2, 256, 0, stream>>>(vf, conv_w, ov, 2 * C, C);

    const size_t n4 = (size_t)out_size / 4;     // 8,388,608 float4s
    addb_kernel<<<(unsigned)(n4 / 256), 256, 0, stream>>>(ou, ov, conv_b, out);
}

// Round 2
// 279.761 us; speedup vs baseline: 2.8130x; 2.8130x over previous
//
#include <hip/hip_runtime.h>
#include <hip/hip_bf16.h>

#define C   64
#define Hh  128
#define Ww  128
#define HW  16384

typedef __attribute__((ext_vector_type(8))) short bf16x8;
typedef __attribute__((ext_vector_type(4))) float f32x4;

__device__ __forceinline__ unsigned short f2bf(float f) {
    unsigned u = __builtin_bit_cast(unsigned, f);
    unsigned r = (u + 0x7fff + ((u >> 16) & 1)) >> 16;
    return (unsigned short)r;
}

// ---------------------------------------------------------------------------
// Prep: fold BN scale into 1x1 proj weights (bf16), compute shifts, and pack
// conv weights to wp[ch2][tap9][co64][ci32] bf16 for each conv half.
// ---------------------------------------------------------------------------
__global__ __launch_bounds__(256) void prep_kernel(
    const float* __restrict__ pu_w, const float* __restrict__ pu_g,
    const float* __restrict__ pu_b, const float* __restrict__ pu_m,
    const float* __restrict__ pu_v,
    const float* __restrict__ pv_w, const float* __restrict__ pv_g,
    const float* __restrict__ pv_b, const float* __restrict__ pv_m,
    const float* __restrict__ pv_v,
    const float* __restrict__ conv_w,
    short* __restrict__ pwu, short* __restrict__ pwv,
    short* __restrict__ wpu, short* __restrict__ wpv,
    float* __restrict__ shu, float* __restrict__ shv)
{
    const int idx = blockIdx.x * 256 + threadIdx.x;
    if (idx < 8192) {                       // proj weights, scale-folded
        const int c  = idx >> 12;
        const int r  = idx & 4095;
        const int co = r >> 6, ci = r & 63;
        const float* w = c ? pv_w : pu_w;
        const float* g = c ? pv_g : pu_g;
        const float* vv = c ? pv_v : pu_v;
        const float scale = g[co] * rsqrtf(vv[co] + 1e-5f);
        (c ? pwv : pwu)[r] = (short)f2bf(w[co * 64 + ci] * scale);
    } else if (idx < 81920) {               // conv weights repack
        const int flat = idx - 8192;
        const int c  = flat / 36864;
        const int r  = flat % 36864;
        const int ch  = r / 18432;
        const int r2  = r % 18432;
        const int tap = r2 / 2048;
        const int r3  = r2 & 2047;
        const int co = r3 >> 5, ci = r3 & 31;
        const float src = conv_w[(size_t)(co * 128 + c * 64 + ch * 32 + ci) * 9 + tap];
        (c ? wpv : wpu)[((ch * 9 + tap) * 64 + co) * 32 + ci] = (short)f2bf(src);
    } else if (idx < 82048) {               // shifts
        const int r  = idx - 81920;
        const int c  = r >> 6, co = r & 63;
        const float* g = c ? pv_g : pu_g;
        const float* b = c ? pv_b : pu_b;
        const float* m = c ? pv_m : pu_m;
        const float* vv = c ? pv_v : pu_v;
        const float scale = g[co] * rsqrtf(vv[co] + 1e-5f);
        (c ? shv : shu)[co] = b[co] - m[co] * scale;
    }
}

// ---------------------------------------------------------------------------
// Proj: y[img][pix][co] = bf16(relu( sum_ci x[img][ci][pix]*pw[co][ci] + shift[co] ))
// MFMA 16x16x32 bf16, M=pix, N=co, K=64. Block: 256 px, 4 waves x 64 px.
// ---------------------------------------------------------------------------
__global__ __launch_bounds__(256) void proj_mfma(
    const float* __restrict__ x, const short* __restrict__ pw,
    const float* __restrict__ shiftg, short* __restrict__ y)
{
    __shared__ short xs[256 * 72];      // [pix][64ci + 8 pad] bf16
    __shared__ short pwl[64 * 72];      // [co][64ci + 8 pad]
    __shared__ float ssh[64];

    const int img  = blockIdx.y;
    const int pix0 = blockIdx.x * 256;
    const int tid  = threadIdx.x;

    // ---- stage x: transpose [ci][pix] fp32 -> [pix][ci] bf16 ----
    const float* xi = x + (size_t)img * C * HW + pix0 + tid;
#pragma unroll 8
    for (int c2 = 0; c2 < 32; ++c2) {
        const float a = xi[(size_t)(2 * c2) * HW];
        const float b = xi[(size_t)(2 * c2 + 1) * HW];
        const int packed = (int)f2bf(a) | ((int)f2bf(b) << 16);
        *(int*)(&xs[tid * 72 + c2 * 2]) = packed;
    }
    // ---- stage weights (16B chunks) + shift ----
#pragma unroll
    for (int it = 0; it < 2; ++it) {
        const int idx = tid + it * 256;      // 512 chunks
        const int oct = idx & 7, co = idx >> 3;
        *(int4*)(&pwl[co * 72 + oct * 8]) = *(const int4*)(&pw[co * 64 + oct * 8]);
    }
    if (tid < 64) ssh[tid] = shiftg[tid];
    __syncthreads();

    const int wq = tid >> 6;
    const int lane = tid & 63;
    const int lx = lane & 15;
    const int q  = lane >> 4;

    f32x4 acc[4][4];
#pragma unroll
    for (int mt = 0; mt < 4; ++mt)
#pragma unroll
        for (int nt = 0; nt < 4; ++nt) acc[mt][nt] = (f32x4){0.f, 0.f, 0.f, 0.f};

#pragma unroll
    for (int kc = 0; kc < 2; ++kc) {
        bf16x8 a[4], b[4];
#pragma unroll
        for (int mt = 0; mt < 4; ++mt)
            a[mt] = *(const bf16x8*)&xs[((wq * 4 + mt) * 16 + lx) * 72 + kc * 32 + q * 8];
#pragma unroll
        for (int nt = 0; nt < 4; ++nt)
            b[nt] = *(const bf16x8*)&pwl[(nt * 16 + lx) * 72 + kc * 32 + q * 8];
#pragma unroll
        for (int mt = 0; mt < 4; ++mt)
#pragma unroll
            for (int nt = 0; nt < 4; ++nt)
                acc[mt][nt] = __builtin_amdgcn_mfma_f32_16x16x32_bf16(a[mt], b[nt], acc[mt][nt], 0, 0, 0);
    }

    // ---- epilogue: +shift, relu, bf16, store [pix][co] ----
    short* yo = y + ((size_t)img * HW + pix0) * C;
#pragma unroll
    for (int mt = 0; mt < 4; ++mt)
#pragma unroll
        for (int nt = 0; nt < 4; ++nt)
#pragma unroll
            for (int r = 0; r < 4; ++r) {
                const int pixl = (wq * 4 + mt) * 16 + q * 4 + r;
                const int co = nt * 16 + lx;
                float vv = acc[mt][nt][r] + ssh[co];
                vv = fmaxf(vv, 0.f);
                yo[(size_t)pixl * C + co] = (short)f2bf(vv);
            }
}

// ---------------------------------------------------------------------------
// Conv 3x3 pad=1 via implicit GEMM MFMA 16x16x32 bf16.
// M=co(64), N=pixels. Block: 32w x 8h = 256 px, 4 waves, each 64co x 64px.
// K = 2 cihalf x 9 tap x 32ci. Activations uf[img][pix][ci] bf16.
// Weights wp[ch][tap][co][32ci] bf16, staged per (ch, tapgroup).
// Output ou[img][co][hw] fp32 (coalesced: C-frag col = pixel).
// ---------------------------------------------------------------------------
__global__ __launch_bounds__(256, 2) void conv_mfma(
    const short* __restrict__ uf, const short* __restrict__ wp,
    float* __restrict__ out)
{
    __shared__ short xs[340 * 40];        // [10h x 34w][32ci + 8 pad]
    __shared__ short wsm[5 * 64 * 40];    // [tap<=5][co][32ci + 8 pad]

    const int img = blockIdx.y;
    const int tx = blockIdx.x & 3, ty = blockIdx.x >> 2;
    const int h0 = ty * 8, w0 = tx * 32;
    const int tid = threadIdx.x;
    const int wq = tid >> 6;
    const int lane = tid & 63;
    const int lx = lane & 15;
    const int q8 = (lane >> 4) * 8;

    f32x4 acc[4][4];
#pragma unroll
    for (int mt = 0; mt < 4; ++mt)
#pragma unroll
        for (int nt = 0; nt < 4; ++nt) acc[mt][nt] = (f32x4){0.f, 0.f, 0.f, 0.f};

    const short* ub = uf + (size_t)img * HW * C;

    for (int ch = 0; ch < 2; ++ch) {
        __syncthreads();
        // ---- stage activations halo: 10 x 34 x 4 octs of 8 ci ----
        for (int idx = tid; idx < 1360; idx += 256) {
            const int oct = idx & 3;
            const int pcell = idx >> 2;
            const int h = pcell / 34, w = pcell - h * 34;
            const int gh = h0 - 1 + h, gw = w0 - 1 + w;
            int4 v = {0, 0, 0, 0};
            if (gh >= 0 && gh < Hh && gw >= 0 && gw < Ww)
                v = *(const int4*)&ub[(size_t)(gh * Ww + gw) * C + ch * 32 + oct * 8];
            *(int4*)(&xs[pcell * 40 + oct * 8]) = v;
        }
        for (int tg = 0; tg < 2; ++tg) {
            const int tb = tg ? 5 : 0;
            const int ntap = tg ? 4 : 5;
            if (tg) __syncthreads();   // protect wsm from previous compute
            // ---- stage weights for this tap group ----
            for (int idx = tid; idx < ntap * 256; idx += 256) {
                const int oct = idx & 3;
                const int co = (idx >> 2) & 63;
                const int tl = idx >> 8;
                *(int4*)(&wsm[(tl * 64 + co) * 40 + oct * 8]) =
                    *(const int4*)&wp[(((ch * 9 + tb + tl) * 64) + co) * 32 + oct * 8];
            }
            __syncthreads();
            // ---- compute ----
            for (int tl = 0; tl < ntap; ++tl) {
                const int t = tb + tl;
                const int ky = (t < 3) ? 0 : ((t < 6) ? 1 : 2);
                const int kx = t - ky * 3;
                bf16x8 a[4], b[4];
#pragma unroll
                for (int mt = 0; mt < 4; ++mt)
                    a[mt] = *(const bf16x8*)&wsm[(tl * 64 + mt * 16 + lx) * 40 + q8];
#pragma unroll
                for (int nt = 0; nt < 4; ++nt) {
                    const int cell = (2 * wq + (nt >> 1) + ky) * 34 + (nt & 1) * 16 + lx + kx;
                    b[nt] = *(const bf16x8*)&xs[cell * 40 + q8];
                }
#pragma unroll
                for (int mt = 0; mt < 4; ++mt)
#pragma unroll
                    for (int nt = 0; nt < 4; ++nt)
                        acc[mt][nt] = __builtin_amdgcn_mfma_f32_16x16x32_bf16(a[mt], b[nt], acc[mt][nt], 0, 0, 0);
            }
        }
    }

    // ---- epilogue: store ou[img][co][h][w] fp32, coalesced over pixels ----
    const int qq = lane >> 4;
    float* ob = out + (size_t)img * C * HW;
#pragma unroll
    for (int mt = 0; mt < 4; ++mt)
#pragma unroll
        for (int nt = 0; nt < 4; ++nt)
#pragma unroll
            for (int r = 0; r < 4; ++r) {
                const int co = mt * 16 + qq * 4 + r;
                const int h = h0 + 2 * wq + (nt >> 1);
                const int w = w0 + (nt & 1) * 16 + lx;
                ob[(size_t)co * HW + h * Ww + w] = acc[mt][nt][r];
            }
}

// ---------------------------------------------------------------------------
// Cross broadcast add (unchanged): out[b,sx,sy,co,hw] = ou[b4+sx] + ov[b4+sy] + bias
// ---------------------------------------------------------------------------
__global__ __launch_bounds__(256) void addb_kernel(
    const float* __restrict__ ou, const float* __restrict__ ov,
    const float* __restrict__ bias, float* __restrict__ out)
{
    const size_t i4 = (size_t)blockIdx.x * 256 + threadIdx.x;
    const int    hw4 = (int)(i4 & 4095);
    const size_t q   = i4 >> 12;
    const int co = (int)(q & 63);
    const size_t p = q >> 6;
    const int sy = (int)(p & 3);
    const int sx = (int)((p >> 2) & 3);
    const int b  = (int)(p >> 4);

    const float4 o1 = ((const float4*)ou)[((size_t)(b * 4 + sx) * C + co) * 4096 + hw4];
    const float4 o2 = ((const float4*)ov)[((size_t)(b * 4 + sy) * C + co) * 4096 + hw4];
    const float bb = bias[co];
    float4 r;
    r.x = o1.x + o2.x + bb;
    r.y = o1.y + o2.y + bb;
    r.z = o1.z + o2.z + bb;
    r.w = o1.w + o2.w + bb;
    ((float4*)out)[i4] = r;
}

// ---------------------------------------------------------------------------
extern "C" void kernel_launch(void* const* d_in, const int* in_sizes, int n_in,
                              void* d_out, int out_size, void* d_ws, size_t ws_size,
                              hipStream_t stream)
{
    const float* u        = (const float*)d_in[0];
    const float* v        = (const float*)d_in[1];
    const float* pu_w     = (const float*)d_in[2];
    const float* pu_gamma = (const float*)d_in[3];
    const float* pu_beta  = (const float*)d_in[4];
    const float* pu_mean  = (const float*)d_in[5];
    const float* pu_var   = (const float*)d_in[6];
    const float* pv_w     = (const float*)d_in[7];
    const float* pv_gamma = (const float*)d_in[8];
    const float* pv_beta  = (const float*)d_in[9];
    const float* pv_mean  = (const float*)d_in[10];
    const float* pv_var   = (const float*)d_in[11];
    const float* conv_w   = (const float*)d_in[12];
    const float* conv_b   = (const float*)d_in[13];
    float* out = (float*)d_out;

    char* ws = (char*)d_ws;
    short* uf  = (short*)(ws);                         // 16,777,216 B
    short* vf  = (short*)(ws + 16777216);              // 16,777,216 B
    float* ou  = (float*)(ws + 33554432);              // 33,554,432 B
    float* ov  = (float*)(ws + 67108864);              // 33,554,432 B
    char*  aux = ws + 100663296;
    short* pwu = (short*)(aux);                        // 8192 B
    short* pwv = (short*)(aux + 8192);                 // 8192 B
    short* wpu = (short*)(aux + 16384);                // 73,728 B
    short* wpv = (short*)(aux + 90112);                // 73,728 B
    float* shu = (float*)(aux + 163840);               // 256 B
    float* shv = (float*)(aux + 164096);               // 256 B

    prep_kernel<<<321, 256, 0, stream>>>(pu_w, pu_gamma, pu_beta, pu_mean, pu_var,
                                         pv_w, pv_gamma, pv_beta, pv_mean, pv_var,
                                         conv_w, pwu, pwv, wpu, wpv, shu, shv);

    dim3 gp(64, 8);
    proj_mfma<<<gp, 256, 0, stream>>>(u, pwu, shu, uf);
    proj_mfma<<<gp, 256, 0, stream>>>(v, pwv, shv, vf);

    dim3 gc(64, 8);
    conv_mfma<<<gc, 256, 0, stream>>>(uf, wpu, ou);
    conv_mfma<<<gc, 256, 0, stream>>>(vf, wpv, ov);

    const size_t n4 = (size_t)out_size / 4;
    addb_kernel<<<(unsigned)(n4 / 256), 256, 0, stream>>>(ou, ov, conv_b, out);
}